// Round 9
// baseline (186.031 us; speedup 1.0000x reference)
//
#include <hip/hip_runtime.h>
#include <hip/hip_bf16.h>
#include <hip/hip_fp16.h>

// Problem constants (match reference)
#define CUTOFF_C    12.0f
#define CUTOFF_SR_C 2.0f
#define CUTOFF_SQ_C 144.0f
#define KEHALF_C    7.199822675975274f

__device__ __forceinline__ float edge_energy(float d, float qi, float qj,
                                             float di, float dj) {
    float inv_d   = __frcp_rn(d);
    float dsh     = __fsqrt_rn(fmaf(d, d, 1.0f));
    float inv_dsh = __frcp_rn(dsh);
    float x  = d * (1.0f / CUTOFF_SR_C);
    float x3 = x * x * x;
    float sw = fmaf(x3, fmaf(x, fmaf(x, -6.0f, 15.0f), -10.0f), 1.0f);
    float sw_off = (d < CUTOFF_SR_C) ? sw : 0.0f;
    float Eoq = inv_d   + fmaf(d,   (1.0f / CUTOFF_SQ_C), -(2.0f / CUTOFF_C));
    float Esq = inv_dsh + fmaf(dsh, (1.0f / CUTOFF_SQ_C), -(2.0f / CUTOFF_C));
    float Eq  = (KEHALF_C * qi * qj) * fmaf(sw_off, Esq - Eoq, Eoq);
    float Eod = inv_d * inv_d * inv_d;
    float Esd = inv_dsh * inv_dsh * inv_dsh;
    float Ed  = (KEHALF_C * di * dj) * fmaf(sw_off, Esd - Eod, Eod);
    return Eq + Ed;
}

// Pack {q, dip} -> half2 (4 B / atom).
__global__ __launch_bounds__(256) void pc_pack_qd_h(
    const float* __restrict__ q,
    const float* __restrict__ dip,
    __half2*     __restrict__ qd,
    int n_atoms)
{
    int a = blockIdx.x * 256 + threadIdx.x;
    if (a < n_atoms) qd[a] = __floats2half2_rn(q[a], dip[a]);
}

// v = KEHALF*qj*F(d), w = KEHALF*dj*G(d) packed as 2xfp16 in one uint.
// out[i] = qi*sum(v) + di*sum(w) — i-side gather eliminated here.
__device__ __forceinline__ unsigned vw_pack(float d, __half2 hqdj) {
    if (!(d <= CUTOFF_C)) return 0u;
    float2 qdj   = __half22float2(hqdj);
    float inv_d   = __frcp_rn(d);
    float dsh     = __fsqrt_rn(fmaf(d, d, 1.0f));
    float inv_dsh = __frcp_rn(dsh);
    float x  = d * (1.0f / CUTOFF_SR_C);
    float x3 = x * x * x;
    float sw = fmaf(x3, fmaf(x, fmaf(x, -6.0f, 15.0f), -10.0f), 1.0f);
    float sw_off = (d < CUTOFF_SR_C) ? sw : 0.0f;
    float Foq = inv_d   + fmaf(d,   (1.0f / CUTOFF_SQ_C), -(2.0f / CUTOFF_C));
    float Fsq = inv_dsh + fmaf(dsh, (1.0f / CUTOFF_SQ_C), -(2.0f / CUTOFF_C));
    float F   = fmaf(sw_off, Fsq - Foq, Foq);
    float God = inv_d * inv_d * inv_d;
    float Gsd = inv_dsh * inv_dsh * inv_dsh;
    float G   = fmaf(sw_off, Gsd - God, God);
    __half2 r = __floats2half2_rn(KEHALF_C * qdj.x * F, KEHALF_C * qdj.y * G);
    union { __half2 h; unsigned u; } cvt;
    cvt.h = r;
    return cvt.u;
}

// 2 groups/thread (g and g+nhalf, both coalesced): 8 independent qd gathers
// + 4 stream loads in flight per thread — double the MLP of the 1-group
// version that measured ~32 us (gather-path ~0.4 lanes/cy with 4 in flight).
__global__ __launch_bounds__(256) void pc_compute_vw(
    const __half2* __restrict__ qd,
    const float*   __restrict__ dist,
    const int*     __restrict__ idx_j,
    unsigned*      __restrict__ vw,
    int n_edges, int n4, int nhalf)
{
    int t = blockIdx.x * 256 + threadIdx.x;
    const int4*   idxj4 = (const int4*)idx_j;
    const float4* dist4 = (const float4*)dist;

    if (t < nhalf) {
        int ga = t;
        int gb = t + nhalf;
        bool hb = (gb < n4);

        int4 ja = idxj4[ga];
        int4 jb = hb ? idxj4[gb] : make_int4(0, 0, 0, 0);

        // 8 gathers issued before any use
        __half2 h0 = qd[ja.x];
        __half2 h1 = qd[ja.y];
        __half2 h2 = qd[ja.z];
        __half2 h3 = qd[ja.w];
        __half2 h4 = qd[jb.x];
        __half2 h5 = qd[jb.y];
        __half2 h6 = qd[jb.z];
        __half2 h7 = qd[jb.w];

        float4 da = dist4[ga];
        float4 db = hb ? dist4[gb] : make_float4(99.f, 99.f, 99.f, 99.f);

        uint4 oa, ob;
        oa.x = vw_pack(da.x, h0);
        oa.y = vw_pack(da.y, h1);
        oa.z = vw_pack(da.z, h2);
        oa.w = vw_pack(da.w, h3);
        ((uint4*)vw)[ga] = oa;
        if (hb) {
            ob.x = vw_pack(db.x, h4);
            ob.y = vw_pack(db.y, h5);
            ob.z = vw_pack(db.z, h6);
            ob.w = vw_pack(db.w, h7);
            ((uint4*)vw)[gb] = ob;
        }
    }

    // scalar tail (n_edges % 4)
    int total = gridDim.x * 256;
    for (int e = (n4 << 2) + t; e < n_edges; e += total) {
        float d = dist[e];
        vw[e] = (d <= CUTOFF_C) ? vw_pack(d, qd[idx_j[e]]) : 0u;
    }
}

// Filter-scatter, depth-2 software pipeline: group g+BLK's stream loads are
// issued before processing group g, so each wave keeps 4 stream loads + 4
// gathers outstanding (was 2 — measured latency-bound at 33% occ, 13% VALU).
template <int CH, int BLK>
__global__ __launch_bounds__(BLK) void pc_scatter_g(
    const int*      __restrict__ idx_i,
    const unsigned* __restrict__ vw,
    const __half2*  __restrict__ qd,
    float*          __restrict__ partial,   // [S][n_atoms]
    int n_edges, int n4, int S, int gps, int n_atoms, int nch)
{
    extern __shared__ float acc[];          // CH floats

    const int c    = blockIdx.x % nch;
    const int s    = blockIdx.x / nch;
    const int base = c * CH;
    const int lim  = min(CH, n_atoms - base);

    for (int i = threadIdx.x; i < CH; i += BLK) acc[i] = 0.0f;
    __syncthreads();

    const int g0 = s * gps;
    const int g1 = min(g0 + gps, n4);
    const int4*  idxi4 = (const int4*)idx_i;
    const uint4* vw4   = (const uint4*)vw;

    const __half2 hzero = __floats2half2_rn(0.0f, 0.0f);

    int  g    = g0 + (int)threadIdx.x;
    bool have = (g < g1);
    int4  i4 = have ? idxi4[g] : make_int4(0, 0, 0, 0);
    uint4 u4 = have ? vw4[g]   : make_uint4(0, 0, 0, 0);

    while (have) {
        int  gn    = g + BLK;
        bool haven = (gn < g1);
        int4  i4n  = haven ? idxi4[gn] : make_int4(0, 0, 0, 0);
        uint4 u4n  = haven ? vw4[gn]   : make_uint4(0, 0, 0, 0);

        int      ii[4] = { i4.x, i4.y, i4.z, i4.w };
        unsigned uu[4] = { u4.x, u4.y, u4.z, u4.w };
        unsigned lc[4];
        bool     vl[4];
        __half2  qh[4];

        #pragma unroll
        for (int k = 0; k < 4; ++k) {
            lc[k] = (unsigned)(ii[k] - base);
            vl[k] = (lc[k] < (unsigned)CH) && (uu[k] != 0u);
        }
        #pragma unroll
        for (int k = 0; k < 4; ++k)
            qh[k] = vl[k] ? qd[ii[k]] : hzero;
        #pragma unroll
        for (int k = 0; k < 4; ++k) {
            if (vl[k]) {
                union { unsigned u; __half2 h; } cvt; cvt.u = uu[k];
                float2 vf = __half22float2(cvt.h);
                float2 qi = __half22float2(qh[k]);
                atomicAdd(&acc[lc[k]], fmaf(qi.x, vf.x, qi.y * vf.y));
            }
        }

        g = gn; have = haven; i4 = i4n; u4 = u4n;
    }

    if (s == S - 1) {  // scalar tail (n_edges % 4)
        for (int e = (n4 << 2) + (int)threadIdx.x; e < n_edges; e += BLK) {
            int i = idx_i[e];
            unsigned local = (unsigned)(i - base);
            unsigned u = vw[e];
            if (local < (unsigned)CH && u != 0u) {
                union { unsigned uu; __half2 h; } cvt; cvt.uu = u;
                float2 vf = __half22float2(cvt.h);
                float2 qi = __half22float2(qd[i]);
                atomicAdd(&acc[local], fmaf(qi.x, vf.x, qi.y * vf.y));
            }
        }
    }

    __syncthreads();
    float* row = partial + (size_t)s * n_atoms + base;
    for (int i = threadIdx.x; i < lim; i += BLK) row[i] = acc[i];
}

// out[a] = sum_s partial[s][a]; 4 waves/block, 64 atoms/block, LDS combine.
__global__ __launch_bounds__(256) void pc_reduce(
    const float* __restrict__ partial,
    float*       __restrict__ out,
    int n_atoms, int S)
{
    __shared__ float sh[256];
    int a0   = blockIdx.x * 64;
    int lane = threadIdx.x & 63;
    int w    = threadIdx.x >> 6;
    int a    = a0 + lane;

    float v0 = 0.0f, v1 = 0.0f;
    if (a < n_atoms) {
        int per = S >> 2;                 // S % 4 == 0
        const float* p = partial + a;
        int s = w * per, send = s + per;
        for (; s + 2 <= send; s += 2) {
            v0 += p[(size_t)(s + 0) * n_atoms];
            v1 += p[(size_t)(s + 1) * n_atoms];
        }
        for (; s < send; ++s) v0 += p[(size_t)s * n_atoms];
    }
    sh[threadIdx.x] = v0 + v1;
    __syncthreads();
    if (w == 0 && a < n_atoms)
        out[a] = (sh[lane] + sh[64 + lane]) + (sh[128 + lane] + sh[192 + lane]);
}

// Full-precision global-atomic fallback (tiny ws only).
__global__ __launch_bounds__(256) void pc_dipole_edges_atomic(
    const float* __restrict__ q,
    const float* __restrict__ dip,
    const float* __restrict__ dist,
    const int*   __restrict__ idx_i,
    const int*   __restrict__ idx_j,
    float*       __restrict__ out,
    int n_edges)
{
    int t = blockIdx.x * blockDim.x + threadIdx.x;
    const int stride = gridDim.x * blockDim.x;
    for (int e = t; e < n_edges; e += stride) {
        float d = dist[e];
        if (d > CUTOFF_C) continue;
        int i = idx_i[e], j = idx_j[e];
        atomicAdd(&out[i], edge_energy(d, q[i], q[j], dip[i], dip[j]));
    }
}

// Tiers:
//  0: CH=33792 (132 KB LDS), BLK 1024, nch=3, S=84  -> 252 blocks, 1/CU, no tail
//  1: CH=20480 ( 80 KB LDS), BLK  512, nch=5, S=100 -> 500 blocks, 2/CU
//  2: CH=16384 ( 64 KB LDS), BLK  512, nch=7, S=72  -> 504 blocks, 2/CU
#define CH_T0 33792
#define CH_T1 20480
#define CH_T2 16384

static bool probe_lds(const void* f, int blk, size_t lds) {
    hipError_t e1 = hipFuncSetAttribute(
        f, hipFuncAttributeMaxDynamicSharedMemorySize, (int)lds);
    int nb = 0;
    hipError_t e2 = hipOccupancyMaxActiveBlocksPerMultiprocessor(&nb, f, blk, lds);
    return (e1 == hipSuccess && e2 == hipSuccess && nb >= 1);
}

extern "C" void kernel_launch(void* const* d_in, const int* in_sizes, int n_in,
                              void* d_out, int out_size, void* d_ws, size_t ws_size,
                              hipStream_t stream) {
    const float* q     = (const float*)d_in[0];
    const float* dip   = (const float*)d_in[1];
    const float* dist  = (const float*)d_in[2];
    const int*   idx_i = (const int*)d_in[3];
    const int*   idx_j = (const int*)d_in[4];
    float*       out   = (float*)d_out;

    int n_edges = in_sizes[2];
    int n_atoms = out_size;
    int n4      = n_edges >> 2;

    // Pick LDS tier (host-only probes; identical work every call).
    int tier, CH, BLK, S;
    size_t lds;
    if (probe_lds((const void*)&pc_scatter_g<CH_T0, 1024>, 1024,
                  (size_t)CH_T0 * 4)) {
        tier = 0; CH = CH_T0; BLK = 1024; S = 84;  lds = (size_t)CH_T0 * 4;
    } else if (probe_lds((const void*)&pc_scatter_g<CH_T1, 512>, 512,
                         (size_t)CH_T1 * 4)) {
        tier = 1; CH = CH_T1; BLK = 512;  S = 100; lds = (size_t)CH_T1 * 4;
    } else {
        tier = 2; CH = CH_T2; BLK = 512;  S = 72;  lds = (size_t)CH_T2 * 4;
    }
    int nch = (n_atoms + CH - 1) / CH;

    // Workspace: [qd half2][vw uint][partial S*n_atoms f32]
    size_t qd_b = ((size_t)n_atoms * sizeof(__half2)  + 255) & ~(size_t)255;
    size_t vw_b = ((size_t)n_edges * sizeof(unsigned) + 255) & ~(size_t)255;
    size_t head = qd_b + vw_b;
    size_t avail = (ws_size > head) ? ws_size - head : 0;
    int S_fit = (int)(avail / ((size_t)n_atoms * sizeof(float)));
    if (S_fit < S) S = S_fit & ~3;

    if (S >= 8 && n_atoms > 0) {
        __half2*  qd      = (__half2*)d_ws;
        unsigned* vw      = (unsigned*)((char*)d_ws + qd_b);
        float*    partial = (float*)((char*)d_ws + head);
        int       gps     = (n4 + S - 1) / S;

        pc_pack_qd_h<<<(n_atoms + 255) / 256, 256, 0, stream>>>(q, dip, qd,
                                                                n_atoms);
        int nhalf = (n4 + 1) / 2;
        int grid1 = (nhalf + 255) / 256;
        if (grid1 < 1) grid1 = 1;
        pc_compute_vw<<<grid1, 256, 0, stream>>>(qd, dist, idx_j, vw,
                                                 n_edges, n4, nhalf);
        if (tier == 0)
            pc_scatter_g<CH_T0, 1024><<<S * nch, 1024, lds, stream>>>(
                idx_i, vw, qd, partial, n_edges, n4, S, gps, n_atoms, nch);
        else if (tier == 1)
            pc_scatter_g<CH_T1, 512><<<S * nch, 512, lds, stream>>>(
                idx_i, vw, qd, partial, n_edges, n4, S, gps, n_atoms, nch);
        else
            pc_scatter_g<CH_T2, 512><<<S * nch, 512, lds, stream>>>(
                idx_i, vw, qd, partial, n_edges, n4, S, gps, n_atoms, nch);
        pc_reduce<<<(n_atoms + 63) / 64, 256, 0, stream>>>(partial, out,
                                                           n_atoms, S);
    } else {
        hipMemsetAsync(out, 0, (size_t)n_atoms * sizeof(float), stream);
        int grid = (n_edges + 255) / 256;
        pc_dipole_edges_atomic<<<grid, 256, 0, stream>>>(
            q, dip, dist, idx_i, idx_j, out, n_edges);
    }
}

// Round 10
// 165.844 us; speedup vs baseline: 1.1217x; 1.1217x over previous
//
#include <hip/hip_runtime.h>
#include <hip/hip_bf16.h>
#include <hip/hip_fp16.h>

// Problem constants (match reference)
#define CUTOFF_C    12.0f
#define CUTOFF_SR_C 2.0f
#define CUTOFF_SQ_C 144.0f
#define KEHALF_C    7.199822675975274f

__device__ __forceinline__ float edge_energy(float d, float qi, float qj,
                                             float di, float dj) {
    float inv_d   = __frcp_rn(d);
    float dsh     = __fsqrt_rn(fmaf(d, d, 1.0f));
    float inv_dsh = __frcp_rn(dsh);
    float x  = d * (1.0f / CUTOFF_SR_C);
    float x3 = x * x * x;
    float sw = fmaf(x3, fmaf(x, fmaf(x, -6.0f, 15.0f), -10.0f), 1.0f);
    float sw_off = (d < CUTOFF_SR_C) ? sw : 0.0f;
    float Eoq = inv_d   + fmaf(d,   (1.0f / CUTOFF_SQ_C), -(2.0f / CUTOFF_C));
    float Esq = inv_dsh + fmaf(dsh, (1.0f / CUTOFF_SQ_C), -(2.0f / CUTOFF_C));
    float Eq  = (KEHALF_C * qi * qj) * fmaf(sw_off, Esq - Eoq, Eoq);
    float Eod = inv_d * inv_d * inv_d;
    float Esd = inv_dsh * inv_dsh * inv_dsh;
    float Ed  = (KEHALF_C * di * dj) * fmaf(sw_off, Esd - Eod, Eod);
    return Eq + Ed;
}

// Radial factors: v = KEHALF*qj*F(d), w = KEHALF*dj*G(d).
// out[i] = qi*sum_j(v) + di*sum_j(w) — recombination happens in the reduce
// with EXACT fp32 q/dip, so the i-side has no fp16 quantization at all.
__device__ __forceinline__ __half2 vw_make(float d, __half2 hqdj) {
    float2 qdj    = __half22float2(hqdj);
    float inv_d   = __frcp_rn(d);
    float dsh     = __fsqrt_rn(fmaf(d, d, 1.0f));
    float inv_dsh = __frcp_rn(dsh);
    float x  = d * (1.0f / CUTOFF_SR_C);
    float x3 = x * x * x;
    float sw = fmaf(x3, fmaf(x, fmaf(x, -6.0f, 15.0f), -10.0f), 1.0f);
    float sw_off = (d < CUTOFF_SR_C) ? sw : 0.0f;
    float Foq = inv_d   + fmaf(d,   (1.0f / CUTOFF_SQ_C), -(2.0f / CUTOFF_C));
    float Fsq = inv_dsh + fmaf(dsh, (1.0f / CUTOFF_SQ_C), -(2.0f / CUTOFF_C));
    float F   = fmaf(sw_off, Fsq - Foq, Foq);
    float God = inv_d * inv_d * inv_d;
    float Gsd = inv_dsh * inv_dsh * inv_dsh;
    float G   = fmaf(sw_off, Gsd - God, God);
    return __floats2half2_rn(KEHALF_C * qdj.x * F, KEHALF_C * qdj.y * G);
}

// half2 atomic add with SFINAE: prefers hardware atomicAdd(__half2*)
// (ds_pk_add_f16 on LDS), falls back to a CAS loop if the overload is
// missing in this ROCm's headers.
__device__ __forceinline__ unsigned h2bits(__half2 h) {
    union { __half2 h; unsigned u; } c; c.h = h; return c.u;
}
__device__ __forceinline__ __half2 bits2h(unsigned u) {
    union { unsigned u; __half2 h; } c; c.u = u; return c.h;
}
template <typename T>
__device__ __forceinline__ auto atom_add_h2(T* p, T v, int)
    -> decltype(atomicAdd(p, v), void()) {
    atomicAdd(p, v);
}
template <typename T>
__device__ __forceinline__ void atom_add_h2(T* p, T v, long) {
    unsigned* u = (unsigned*)p;
    unsigned old = *u, assumed;
    do {
        assumed = old;
        __half2 sum = __hadd2(bits2h(assumed), v);
        old = atomicCAS(u, assumed, h2bits(sum));
    } while (old != assumed);
}

// Pack {q, dip} -> half2 (4 B / atom), j-side gather table.
__global__ __launch_bounds__(256) void pc_pack_qd_h(
    const float* __restrict__ q,
    const float* __restrict__ dip,
    __half2*     __restrict__ qd,
    int n_atoms)
{
    int a = blockIdx.x * 256 + threadIdx.x;
    if (a < n_atoms) qd[a] = __floats2half2_rn(q[a], dip[a]);
}

// Fused compute+scatter: block (s, c) streams slice s of (dist, idx_i,
// idx_j); for survivors (i in chunk c, d <= cutoff) it gathers qd[j]
// (the ONLY divergent gather in the pipeline — 5.66M total, was 12.1M),
// computes {v,w}, and pk-adds into the half2 LDS accumulator.
// Grid is tail-free: S*nch = 252 <= 256 CUs, 1 block/CU (132 KB LDS).
template <int CH, int BLK>
__global__ __launch_bounds__(BLK) void pc_scatter_fused(
    const float*   __restrict__ dist,
    const int*     __restrict__ idx_i,
    const int*     __restrict__ idx_j,
    const __half2* __restrict__ qd,
    __half2*       __restrict__ partial,   // [S][n_atoms] half2 {sumv,sumw}
    int n_edges, int n4, int S, int gps, int n_atoms, int nch)
{
    extern __shared__ __half2 acc2[];      // CH half2 = 4 B/atom

    const int c    = blockIdx.x % nch;
    const int s    = blockIdx.x / nch;
    const int base = c * CH;
    const int lim  = min(CH, n_atoms - base);

    const __half2 hzero = __floats2half2_rn(0.0f, 0.0f);
    for (int i = threadIdx.x; i < CH; i += BLK) acc2[i] = hzero;
    __syncthreads();

    const int g0 = s * gps;
    const int g1 = min(g0 + gps, n4);
    const int4*   idxi4 = (const int4*)idx_i;
    const int4*   idxj4 = (const int4*)idx_j;
    const float4* dist4 = (const float4*)dist;

    for (int g = g0 + (int)threadIdx.x; g < g1; g += BLK) {
        int4   i4 = idxi4[g];
        int4   j4 = idxj4[g];
        float4 d4 = dist4[g];

        int      ii[4] = { i4.x, i4.y, i4.z, i4.w };
        int      jj[4] = { j4.x, j4.y, j4.z, j4.w };
        float    dd[4] = { d4.x, d4.y, d4.z, d4.w };
        unsigned lc[4];
        bool     vl[4];
        __half2  qh[4];

        #pragma unroll
        for (int k = 0; k < 4; ++k) {
            lc[k] = (unsigned)(ii[k] - base);
            vl[k] = (lc[k] < (unsigned)CH) && (dd[k] <= CUTOFF_C);
        }
        // batch the masked gathers so all are in flight before first use
        #pragma unroll
        for (int k = 0; k < 4; ++k)
            qh[k] = vl[k] ? qd[jj[k]] : hzero;
        #pragma unroll
        for (int k = 0; k < 4; ++k) {
            if (vl[k]) {
                __half2 vw = vw_make(dd[k], qh[k]);
                atom_add_h2(&acc2[lc[k]], vw, 0);
            }
        }
    }

    if (s == S - 1) {  // scalar tail (n_edges % 4)
        for (int e = (n4 << 2) + (int)threadIdx.x; e < n_edges; e += BLK) {
            int i = idx_i[e];
            float d = dist[e];
            unsigned local = (unsigned)(i - base);
            if (local < (unsigned)CH && d <= CUTOFF_C) {
                __half2 vw = vw_make(d, qd[idx_j[e]]);
                atom_add_h2(&acc2[local], vw, 0);
            }
        }
    }

    __syncthreads();
    __half2* row = partial + (size_t)s * n_atoms + base;
    for (int i = threadIdx.x; i < lim; i += BLK) row[i] = acc2[i];
}

// out[a] = q[a]*sum_s(v) + dip[a]*sum_s(w) — exact fp32 recombination.
// 4 waves/block each sum S/4 slices for 64 atoms; LDS combine.
__global__ __launch_bounds__(256) void pc_reduce_vw(
    const __half2* __restrict__ partial,   // [S][n_atoms]
    const float*   __restrict__ q,
    const float*   __restrict__ dip,
    float*         __restrict__ out,
    int n_atoms, int S)
{
    __shared__ float2 sh[256];
    int a0   = blockIdx.x * 64;
    int lane = threadIdx.x & 63;
    int w    = threadIdx.x >> 6;
    int a    = a0 + lane;

    float sv = 0.0f, sw = 0.0f;
    if (a < n_atoms) {
        int per = S >> 2;                  // S % 4 == 0
        const __half2* p = partial + a;
        int s = w * per, send = s + per;
        for (; s < send; ++s) {
            float2 t = __half22float2(p[(size_t)s * n_atoms]);
            sv += t.x; sw += t.y;
        }
    }
    sh[threadIdx.x] = make_float2(sv, sw);
    __syncthreads();
    if (w == 0 && a < n_atoms) {
        float2 t0 = sh[lane],       t1 = sh[64 + lane];
        float2 t2 = sh[128 + lane], t3 = sh[192 + lane];
        float fv = (t0.x + t1.x) + (t2.x + t3.x);
        float fw = (t0.y + t1.y) + (t2.y + t3.y);
        out[a] = fmaf(q[a], fv, dip[a] * fw);
    }
}

// Full-precision global-atomic fallback (tiny ws only).
__global__ __launch_bounds__(256) void pc_dipole_edges_atomic(
    const float* __restrict__ q,
    const float* __restrict__ dip,
    const float* __restrict__ dist,
    const int*   __restrict__ idx_i,
    const int*   __restrict__ idx_j,
    float*       __restrict__ out,
    int n_edges)
{
    int t = blockIdx.x * blockDim.x + threadIdx.x;
    const int stride = gridDim.x * blockDim.x;
    for (int e = t; e < n_edges; e += stride) {
        float d = dist[e];
        if (d > CUTOFF_C) continue;
        int i = idx_i[e], j = idx_j[e];
        atomicAdd(&out[i], edge_energy(d, q[i], q[j], dip[i], dip[j]));
    }
}

// Tiers:
//  0: CH=33792 (132 KB LDS), BLK 1024, nch=3, S=84 -> 252 blocks, 1/CU, no tail
//  1: CH=20480 ( 80 KB LDS), BLK  512, nch=5, S=48 -> 240 blocks
#define CH_T0 33792
#define CH_T1 20480

static bool probe_lds(const void* f, int blk, size_t lds) {
    hipError_t e1 = hipFuncSetAttribute(
        f, hipFuncAttributeMaxDynamicSharedMemorySize, (int)lds);
    int nb = 0;
    hipError_t e2 = hipOccupancyMaxActiveBlocksPerMultiprocessor(&nb, f, blk, lds);
    return (e1 == hipSuccess && e2 == hipSuccess && nb >= 1);
}

extern "C" void kernel_launch(void* const* d_in, const int* in_sizes, int n_in,
                              void* d_out, int out_size, void* d_ws, size_t ws_size,
                              hipStream_t stream) {
    const float* q     = (const float*)d_in[0];
    const float* dip   = (const float*)d_in[1];
    const float* dist  = (const float*)d_in[2];
    const int*   idx_i = (const int*)d_in[3];
    const int*   idx_j = (const int*)d_in[4];
    float*       out   = (float*)d_out;

    int n_edges = in_sizes[2];
    int n_atoms = out_size;
    int n4      = n_edges >> 2;

    // Pick LDS tier (host-only probes; identical work every call).
    int tier, CH, BLK, S;
    size_t lds;
    if (probe_lds((const void*)&pc_scatter_fused<CH_T0, 1024>, 1024,
                  (size_t)CH_T0 * 4)) {
        tier = 0; CH = CH_T0; BLK = 1024; S = 84; lds = (size_t)CH_T0 * 4;
    } else {
        tier = 1; CH = CH_T1; BLK = 512;  S = 48; lds = (size_t)CH_T1 * 4;
    }
    int nch = (n_atoms + CH - 1) / CH;

    // Workspace: [qd half2][partial S*n_atoms half2]
    size_t qd_b  = ((size_t)n_atoms * sizeof(__half2) + 255) & ~(size_t)255;
    size_t avail = (ws_size > qd_b) ? ws_size - qd_b : 0;
    int S_fit = (int)(avail / ((size_t)n_atoms * sizeof(__half2)));
    if (S_fit < S) S = S_fit & ~3;

    if (S >= 8 && n_atoms > 0) {
        __half2* qd      = (__half2*)d_ws;
        __half2* partial = (__half2*)((char*)d_ws + qd_b);
        int      gps     = (n4 + S - 1) / S;

        pc_pack_qd_h<<<(n_atoms + 255) / 256, 256, 0, stream>>>(q, dip, qd,
                                                                n_atoms);
        if (tier == 0)
            pc_scatter_fused<CH_T0, 1024><<<S * nch, 1024, lds, stream>>>(
                dist, idx_i, idx_j, qd, partial, n_edges, n4, S, gps,
                n_atoms, nch);
        else
            pc_scatter_fused<CH_T1, 512><<<S * nch, 512, lds, stream>>>(
                dist, idx_i, idx_j, qd, partial, n_edges, n4, S, gps,
                n_atoms, nch);
        pc_reduce_vw<<<(n_atoms + 63) / 64, 256, 0, stream>>>(
            partial, q, dip, out, n_atoms, S);
    } else {
        hipMemsetAsync(out, 0, (size_t)n_atoms * sizeof(float), stream);
        int grid = (n_edges + 255) / 256;
        pc_dipole_edges_atomic<<<grid, 256, 0, stream>>>(
            q, dip, dist, idx_i, idx_j, out, n_edges);
    }
}